// Round 2
// baseline (1565.874 us; speedup 1.0000x reference)
//
#include <hip/hip_runtime.h>

// ROIMaskHead: x[1024,14,14,256] f32 -> 4x (conv3x3 256->256 + relu) ->
// conv_transpose 2x2 s2 + relu -> 1x1 conv ->80, out [1024,28,28,80] f32.
// All matmuls via mfma_f32_16x16x32_f16; activations/weights fp16, acc f32.

typedef _Float16 f16x8 __attribute__((ext_vector_type(8)));
typedef float    f32x4 __attribute__((ext_vector_type(4)));
typedef unsigned short u16;
typedef unsigned int   u32;

__device__ __forceinline__ u16 f2h(float f) {
  union { _Float16 h; u16 u; } c; c.h = (_Float16)f; return c.u;
}

__device__ __forceinline__ void store8(u16* dst, const u16* o) {
  uint4 v;
  v.x = (u32)o[0] | ((u32)o[1] << 16);
  v.y = (u32)o[2] | ((u32)o[3] << 16);
  v.z = (u32)o[4] | ((u32)o[5] << 16);
  v.w = (u32)o[6] | ((u32)o[7] << 16);
  *(uint4*)dst = v;
}

// ---------------------------------------------------------------------------
// Weight repack to MFMA B-fragment order (one coalesced dwordx4 per lane):
// WbP[l][tap][kc][cotile][lane=q*16+rr][j] = Wc[l][tap][ci=kc*32+q*8+j][co=ct*16+rr]
// WtP[ab][kc][ct][lane][j]                = Wt[3-ab][ci][co]   (spatial flip)
// WmP[kc][nt][lane][j]                    = Wm[ci][nc=nt*16+rr]
// ---------------------------------------------------------------------------
__global__ void prep_weights(const float* __restrict__ Wc, const float* __restrict__ Wt,
                             const float* __restrict__ Wm,
                             u16* __restrict__ WbP, u16* __restrict__ WtP,
                             u16* __restrict__ WmP) {
  int id = blockIdx.x * 256 + threadIdx.x;
  u16 o[8];
  if (id < 294912) {
    int li = id & 63; int rest = id >> 6;
    int ct = rest & 15; rest >>= 4;
    int kc = rest & 7;  rest >>= 3;          // rest = l*9+tap (0..35)
    int co  = ct * 16 + (li & 15);
    int ci0 = kc * 32 + (li >> 4) * 8;
#pragma unroll
    for (int j = 0; j < 8; j++) o[j] = f2h(Wc[(rest * 256 + ci0 + j) * 256 + co]);
    store8(&WbP[id * 8], o);
  } else if (id < 327680) {
    int id2 = id - 294912;
    int li = id2 & 63; int rest = id2 >> 6;
    int ct = rest & 15; rest >>= 4;
    int kc = rest & 7;  rest >>= 3;          // rest = ab (0..3)
    int srcq = 3 - rest;                     // kernel flip for conv_transpose
    int co  = ct * 16 + (li & 15);
    int ci0 = kc * 32 + (li >> 4) * 8;
#pragma unroll
    for (int j = 0; j < 8; j++) o[j] = f2h(Wt[(srcq * 256 + ci0 + j) * 256 + co]);
    store8(&WtP[id2 * 8], o);
  } else if (id < 330240) {
    int id3 = id - 327680;
    int li = id3 & 63; int rest = id3 >> 6;  // 0..39
    int kc = rest / 5, nt = rest % 5;
    int nc  = nt * 16 + (li & 15);
    int ci0 = kc * 32 + (li >> 4) * 8;
#pragma unroll
    for (int j = 0; j < 8; j++) o[j] = f2h(Wm[(ci0 + j) * 80 + nc]);
    store8(&WmP[id3 * 8], o);
  }
}

// ---------------------------------------------------------------------------
// conv3x3 SAME, 256->256, relu(x+b). One block = (roi, M-half of 112 px).
// 4 waves x (7 Mtiles x 4 Nfrags); K = 2 ci-halves of 128.
// This round: double-buffered LDS ci-halves (fp16 path). Phase-1 global loads
// are issued into registers BEFORE compute-0 (T14 async-STAGE), written to
// buffer 1 after compute-0 with a single barrier -> staging latency hides
// under MFMA. Windowed rows + tap rotation + B double-prefetch kept from R1.
// Layer 0 (f32 input) keeps serial staging (reg cost too high to prefetch).
// ---------------------------------------------------------------------------
template <bool INF32>
__global__ __launch_bounds__(256, 2)
void conv_layer(const void* __restrict__ in_, const u16* __restrict__ WbP,
                const float* __restrict__ bc, u16* __restrict__ out, int layer) {
  __shared__ u16 sA[2 * 17136 + 128];        // two 126x136 buffers + zero page
  const int BUF = 17136;
  const int ZPI = 2 * 17136;
  const int tid = threadIdx.x;
  const int w = tid >> 6, lane = tid & 63, q = lane >> 4, r = lane & 15;
  const int roi = blockIdx.x, mhalf = blockIdx.y;
  const int mbase = mhalf * 112;
  const int base_px = mhalf ? 98 : 0;      // first staged pixel (row_lo * 14)
  const int n_px   = mhalf ? 98 : 126;     // staged pixel count (rows 7..13 / 0..8)
  const int rot = (blockIdx.x + mhalf) % 9;
  if (tid < 64) ((u32*)(sA + ZPI))[tid] = 0u;

  int py[7], px[7];
#pragma unroll
  for (int mt = 0; mt < 7; mt++) {
    int p = mbase + mt * 16 + r;
    py[mt] = (p < 196) ? (p / 14) : 1000;   // 1000 => always invalid after +dy
    px[mt] = p % 14;
  }
  f32x4 acc[7][4];
#pragma unroll
  for (int mt = 0; mt < 7; mt++)
#pragma unroll
    for (int nf = 0; nf < 4; nf++) acc[mt][nf] = (f32x4){0.f, 0.f, 0.f, 0.f};

  const float* xrow = (const float*)in_ + ((size_t)blockIdx.x * 196 + base_px) * 256;
  const u16*   yrow = (const u16*)in_   + ((size_t)blockIdx.x * 196 + base_px) * 256;

  // per-(wave,lane) weight base; element offset for (tap,kc,nf):
  //   tap*65536 + kc*8192 + nf*512
  const u16* wb = WbP + (size_t)layer * 589824 + (w * 4) * 512 + lane * 8;

  f16x8 b0[4], b1[4];
#pragma unroll
  for (int nf = 0; nf < 4; nf++)
    b0[nf] = *(const f16x8*)&wb[rot * 65536 + nf * 512];   // (tap=rot, kc=0)

  // ---- stage phase 0 (ci 0..127) into buffer 0 ----
  if (INF32) {
    for (int c = tid; c < n_px * 32; c += 256) {
      int pix = c >> 5, c4 = (c & 31) * 4;
      const float4 v = *(const float4*)&xrow[pix * 256 + c4];
      ushort4 h; h.x = f2h(v.x); h.y = f2h(v.y); h.z = f2h(v.z); h.w = f2h(v.w);
      *(ushort4*)&sA[pix * 136 + c4] = h;
    }
  } else {
#pragma unroll
    for (int i = 0; i < 8; i++) {
      int c = tid + i * 256;
      if (c < n_px * 16) {
        int pix = c >> 4, c8 = (c & 15) * 8;
        *(uint4*)&sA[pix * 136 + c8] = *(const uint4*)&yrow[pix * 256 + c8];
      }
    }
  }
  __syncthreads();

  // ---- issue phase-1 loads (ci 128..255) early; they ride out compute-0 ----
  uint4 pre[8];
  if (!INF32) {
#pragma unroll
    for (int i = 0; i < 8; i++) {
      int c = tid + i * 256;
      if (c < n_px * 16) {
        int pix = c >> 4, c8 = (c & 15) * 8;
        pre[i] = *(const uint4*)&yrow[pix * 256 + 128 + c8];
      }
    }
  }

  for (int kh = 0; kh < 2; kh++) {
    if (kh) {
      if (INF32) {
        __syncthreads();                     // all buf0 reads done
        for (int c = tid; c < n_px * 32; c += 256) {
          int pix = c >> 5, c4 = (c & 31) * 4;
          const float4 v = *(const float4*)&xrow[pix * 256 + 128 + c4];
          ushort4 h; h.x = f2h(v.x); h.y = f2h(v.y); h.z = f2h(v.z); h.w = f2h(v.w);
          *(ushort4*)&sA[pix * 136 + c4] = h;
        }
      } else {
#pragma unroll
        for (int i = 0; i < 8; i++) {        // drain prefetch into buffer 1
          int c = tid + i * 256;
          if (c < n_px * 16) {
            int pix = c >> 4, c8 = (c & 15) * 8;
            *(uint4*)&sA[BUF + pix * 136 + c8] = pre[i];
          }
        }
      }
      __syncthreads();
    }
    const int bufb = INF32 ? 0 : kh * BUF;

    for (int t = 0; t < 9; t++) {
      int tap = t + rot; if (tap >= 9) tap -= 9;
      const int dy = tap / 3 - 1, dx = tap % 3 - 1;
      int offs[7];
#pragma unroll
      for (int mt = 0; mt < 7; mt++) {
        int ny = py[mt] + dy, nx = px[mt] + dx;
        bool v = ((u32)ny < 14u) && ((u32)nx < 14u);
        offs[mt] = v ? (bufb + ((ny * 14 + nx) - base_px) * 136) : ZPI;
      }
#pragma unroll
      for (int kk = 0; kk < 4; kk++) {
        // ---- next pipeline step's (tap, kh, kk) for the B prefetch ----
        int nt = t, nh = kh, nk = kk + 1;
        if (kk == 3) {
          nk = 0; nt = t + 1;
          if (nt == 9) {
            if (kh == 0) { nt = 0; nh = 1; }          // cross into half 1
            else         { nt = 8; nh = 1; nk = 3; }  // very last: benign reload
          }
        }
        int ntap = nt + rot; if (ntap >= 9) ntap -= 9;
        const u16* wn = wb + (ntap * 8 + nh * 4 + nk) * 8192;
        if ((kk & 1) == 0) {
#pragma unroll
          for (int nf = 0; nf < 4; nf++) b1[nf] = *(const f16x8*)&wn[nf * 512];
#pragma unroll
          for (int mt = 0; mt < 7; mt++) {
            f16x8 a = *(const f16x8*)&sA[offs[mt] + kk * 32 + q * 8];
#pragma unroll
            for (int nf = 0; nf < 4; nf++)
              acc[mt][nf] = __builtin_amdgcn_mfma_f32_16x16x32_f16(a, b0[nf], acc[mt][nf], 0, 0, 0);
          }
        } else {
#pragma unroll
          for (int nf = 0; nf < 4; nf++) b0[nf] = *(const f16x8*)&wn[nf * 512];
#pragma unroll
          for (int mt = 0; mt < 7; mt++) {
            f16x8 a = *(const f16x8*)&sA[offs[mt] + kk * 32 + q * 8];
#pragma unroll
            for (int nf = 0; nf < 4; nf++)
              acc[mt][nf] = __builtin_amdgcn_mfma_f32_16x16x32_f16(a, b1[nf], acc[mt][nf], 0, 0, 0);
          }
        }
      }
    }
  }

  float bias[4];
#pragma unroll
  for (int nf = 0; nf < 4; nf++) bias[nf] = bc[layer * 256 + (w * 4 + nf) * 16 + r];
#pragma unroll
  for (int mt = 0; mt < 7; mt++) {
#pragma unroll
    for (int jj = 0; jj < 4; jj++) {
      int p = mbase + mt * 16 + q * 4 + jj;   // C/D: row = q*4+reg, col = r
      if (p < 196) {
#pragma unroll
        for (int nf = 0; nf < 4; nf++) {
          float v = acc[mt][nf][jj] + bias[nf];
          v = fmaxf(v, 0.f);
          out[((size_t)blockIdx.x * 196 + p) * 256 + (w * 4 + nf) * 16 + r] = f2h(v);
        }
      }
    }
  }
  (void)roi;
}

// ---------------------------------------------------------------------------
// Fused transpose-conv (2x2 s2 VALID, per-quadrant 1x1 GEMM) + relu + 1x1 mask.
// Block = (roi, quadrant ab, M-half). Phase 1: T = relu(y4 x WtP[ab] + bt)
// -> LDS tile [112][264] fp16. Phase 2: out = T x Wm + bm (N=80 = 5 tiles).
// This round: same async-STAGE double-buffer of the two ci-halves.
// ---------------------------------------------------------------------------
__global__ __launch_bounds__(256, 2)
void tail_fused(const u16* __restrict__ y4, const u16* __restrict__ WtP,
                const u16* __restrict__ WmP, const float* __restrict__ bt,
                const float* __restrict__ bm, float* __restrict__ out) {
  __shared__ u16 sA[2 * 15232 + 128];        // two 112x136 buffers + ZP; T tile reuses
  const int BUF = 15232;
  const int ZPI = 2 * 15232;
  const int tid = threadIdx.x;
  const int w = tid >> 6, lane = tid & 63, q = lane >> 4, r = lane & 15;
  const int roi = blockIdx.x, ab = blockIdx.y, mbase = blockIdx.z * 112;
  const int n_px = mbase ? 84 : 112;
  if (tid < 64) ((u32*)(sA + ZPI))[tid] = 0u;

  int roffs[7];
#pragma unroll
  for (int mt = 0; mt < 7; mt++) {
    int p = mbase + mt * 16 + r;
    roffs[mt] = (p < 196) ? (mt * 16 + r) * 136 : -1;
  }
  f32x4 acc[7][4];
#pragma unroll
  for (int mt = 0; mt < 7; mt++)
#pragma unroll
    for (int nf = 0; nf < 4; nf++) acc[mt][nf] = (f32x4){0.f, 0.f, 0.f, 0.f};

  const u16* yrow = y4 + ((size_t)roi * 196 + mbase) * 256;

  const u16* wt = WtP + ab * 65536 + (w * 4) * 512 + lane * 8;  // off: kc*8192+nf*512
  f16x8 b0[4], b1[4];
#pragma unroll
  for (int nf = 0; nf < 4; nf++) b0[nf] = *(const f16x8*)&wt[nf * 512];  // kc=0

  // stage phase 0 (ci 0..127)
#pragma unroll
  for (int i = 0; i < 7; i++) {
    int c = tid + i * 256;
    if (c < n_px * 16) {
      int pix = c >> 4, c8 = (c & 15) * 8;
      *(uint4*)&sA[pix * 136 + c8] = *(const uint4*)&yrow[pix * 256 + c8];
    }
  }
  __syncthreads();

  uint4 pre[7];
#pragma unroll
  for (int i = 0; i < 7; i++) {
    int c = tid + i * 256;
    if (c < n_px * 16) {
      int pix = c >> 4, c8 = (c & 15) * 8;
      pre[i] = *(const uint4*)&yrow[pix * 256 + 128 + c8];
    }
  }

  for (int kh = 0; kh < 2; kh++) {
    if (kh) {
#pragma unroll
      for (int i = 0; i < 7; i++) {
        int c = tid + i * 256;
        if (c < n_px * 16) {
          int pix = c >> 4, c8 = (c & 15) * 8;
          *(uint4*)&sA[BUF + pix * 136 + c8] = pre[i];
        }
      }
      __syncthreads();
    }
    const int bufb = kh * BUF;
#pragma unroll
    for (int kk = 0; kk < 4; kk++) {
      int nc_ = kh * 4 + kk + 1; if (nc_ > 7) nc_ = 7;   // next kc (clamped)
      const u16* wn = wt + nc_ * 8192;
      if ((kk & 1) == 0) {
#pragma unroll
        for (int nf = 0; nf < 4; nf++) b1[nf] = *(const f16x8*)&wn[nf * 512];
#pragma unroll
        for (int mt = 0; mt < 7; mt++) {
          int o = (roffs[mt] < 0) ? ZPI : (bufb + roffs[mt]);
          f16x8 a = *(const f16x8*)&sA[o + kk * 32 + q * 8];
#pragma unroll
          for (int nf = 0; nf < 4; nf++)
            acc[mt][nf] = __builtin_amdgcn_mfma_f32_16x16x32_f16(a, b0[nf], acc[mt][nf], 0, 0, 0);
        }
      } else {
#pragma unroll
        for (int nf = 0; nf < 4; nf++) b0[nf] = *(const f16x8*)&wn[nf * 512];
#pragma unroll
        for (int mt = 0; mt < 7; mt++) {
          int o = (roffs[mt] < 0) ? ZPI : (bufb + roffs[mt]);
          f16x8 a = *(const f16x8*)&sA[o + kk * 32 + q * 8];
#pragma unroll
          for (int nf = 0; nf < 4; nf++)
            acc[mt][nf] = __builtin_amdgcn_mfma_f32_16x16x32_f16(a, b1[nf], acc[mt][nf], 0, 0, 0);
        }
      }
    }
  }

  __syncthreads();                           // all K-loop LDS reads done
  float btv[4];
#pragma unroll
  for (int nf = 0; nf < 4; nf++) btv[nf] = bt[(w * 4 + nf) * 16 + r];
#pragma unroll
  for (int mt = 0; mt < 7; mt++) {
#pragma unroll
    for (int jj = 0; jj < 4; jj++) {
      int row = mt * 16 + q * 4 + jj;        // 0..111
#pragma unroll
      for (int nf = 0; nf < 4; nf++) {
        float v = fmaxf(acc[mt][nf][jj] + btv[nf], 0.f);
        sA[row * 264 + (w * 4 + nf) * 16 + r] = f2h(v);
      }
    }
  }
  __syncthreads();

  float bmv[5];
#pragma unroll
  for (int nt = 0; nt < 5; nt++) bmv[nt] = bm[nt * 16 + r];
  const int a_ = ab >> 1, b_ = ab & 1;
  for (int tt = w; tt < 7; tt += 4) {
    f32x4 a2[5];
#pragma unroll
    for (int nt = 0; nt < 5; nt++) a2[nt] = (f32x4){0.f, 0.f, 0.f, 0.f};
#pragma unroll
    for (int kc = 0; kc < 8; kc++) {
      f16x8 af = *(const f16x8*)&sA[(tt * 16 + r) * 264 + kc * 32 + q * 8];
#pragma unroll
      for (int nt = 0; nt < 5; nt++) {
        f16x8 bw = *(const f16x8*)&WmP[((kc * 5 + nt) * 64 + lane) * 8];
        a2[nt] = __builtin_amdgcn_mfma_f32_16x16x32_f16(af, bw, a2[nt], 0, 0, 0);
      }
    }
#pragma unroll
    for (int jj = 0; jj < 4; jj++) {
      int row = tt * 16 + q * 4 + jj;
      int p = mbase + row;
      if (p < 196) {
        int y = p / 14, x = p % 14;
        size_t base = (size_t)roi * 62720 + (2 * y + a_) * 2240 + (2 * x + b_) * 80;
#pragma unroll
        for (int nt = 0; nt < 5; nt++) out[base + nt * 16 + r] = a2[nt][jj] + bmv[nt];
      }
    }
  }
}

// ---------------------------------------------------------------------------
extern "C" void kernel_launch(void* const* d_in, const int* in_sizes, int n_in,
                              void* d_out, int out_size, void* d_ws, size_t ws_size,
                              hipStream_t stream) {
  const float* x  = (const float*)d_in[0];
  const float* Wc = (const float*)d_in[1];
  const float* bc = (const float*)d_in[2];
  const float* Wt = (const float*)d_in[3];
  const float* bt = (const float*)d_in[4];
  const float* Wm = (const float*)d_in[5];
  const float* bm = (const float*)d_in[6];
  float* out = (float*)d_out;

  char* ws = (char*)d_ws;
  u16* WbP = (u16*)(ws);                         // 4,718,592 B
  u16* WtP = (u16*)(ws + 4718592);               //   524,288 B
  u16* WmP = (u16*)(ws + 5242880);               //    40,960 B
  u16* yA  = (u16*)(ws + 6291456);               // 102,760,448 B
  u16* yB  = (u16*)(ws + 6291456 + 102760448);   // 102,760,448 B  (total ~212 MB)

  prep_weights<<<1290, 256, 0, stream>>>(Wc, Wt, Wm, WbP, WtP, WmP);

  dim3 cg(1024, 2);
  conv_layer<true ><<<cg, 256, 0, stream>>>(x,  WbP, bc, yA, 0);
  conv_layer<false><<<cg, 256, 0, stream>>>(yA, WbP, bc, yB, 1);
  conv_layer<false><<<cg, 256, 0, stream>>>(yB, WbP, bc, yA, 2);
  conv_layer<false><<<cg, 256, 0, stream>>>(yA, WbP, bc, yB, 3);

  tail_fused<<<dim3(1024, 4, 2), 256, 0, stream>>>(yB, WtP, WmP, bt, bm, out);
}

// Round 5
// 1499.357 us; speedup vs baseline: 1.0444x; 1.0444x over previous
//
#include <hip/hip_runtime.h>

// ROIMaskHead: x[1024,14,14,256] f32 -> 4x (conv3x3 256->256 + relu) ->
// conv_transpose 2x2 s2 + relu -> 1x1 conv ->80, out [1024,28,28,80] f32.
// All matmuls via mfma_f32_16x16x32_f16; activations/weights fp16, acc f32.

typedef _Float16 f16x8 __attribute__((ext_vector_type(8)));
typedef float    f32x4 __attribute__((ext_vector_type(4)));
typedef unsigned short u16;
typedef unsigned int   u32;

__device__ __forceinline__ u16 f2h(float f) {
  union { _Float16 h; u16 u; } c; c.h = (_Float16)f; return c.u;
}

__device__ __forceinline__ void store8(u16* dst, const u16* o) {
  uint4 v;
  v.x = (u32)o[0] | ((u32)o[1] << 16);
  v.y = (u32)o[2] | ((u32)o[3] << 16);
  v.z = (u32)o[4] | ((u32)o[5] << 16);
  v.w = (u32)o[6] | ((u32)o[7] << 16);
  *(uint4*)dst = v;
}

// ---------------------------------------------------------------------------
// Weight repack to MFMA B-fragment order (one coalesced dwordx4 per lane):
// WbP[l][tap][kc][cotile][lane=q*16+rr][j] = Wc[l][tap][ci=kc*32+q*8+j][co=ct*16+rr]
// WtP[ab][kc][ct][lane][j]                = Wt[3-ab][ci][co]   (spatial flip)
// WmP[kc][nt][lane][j]                    = Wm[ci][nc=nt*16+rr]
// ---------------------------------------------------------------------------
__global__ void prep_weights(const float* __restrict__ Wc, const float* __restrict__ Wt,
                             const float* __restrict__ Wm,
                             u16* __restrict__ WbP, u16* __restrict__ WtP,
                             u16* __restrict__ WmP) {
  int id = blockIdx.x * 256 + threadIdx.x;
  u16 o[8];
  if (id < 294912) {
    int li = id & 63; int rest = id >> 6;
    int ct = rest & 15; rest >>= 4;
    int kc = rest & 7;  rest >>= 3;          // rest = l*9+tap (0..35)
    int co  = ct * 16 + (li & 15);
    int ci0 = kc * 32 + (li >> 4) * 8;
#pragma unroll
    for (int j = 0; j < 8; j++) o[j] = f2h(Wc[(rest * 256 + ci0 + j) * 256 + co]);
    store8(&WbP[id * 8], o);
  } else if (id < 327680) {
    int id2 = id - 294912;
    int li = id2 & 63; int rest = id2 >> 6;
    int ct = rest & 15; rest >>= 4;
    int kc = rest & 7;  rest >>= 3;          // rest = ab (0..3)
    int srcq = 3 - rest;                     // kernel flip for conv_transpose
    int co  = ct * 16 + (li & 15);
    int ci0 = kc * 32 + (li >> 4) * 8;
#pragma unroll
    for (int j = 0; j < 8; j++) o[j] = f2h(Wt[(srcq * 256 + ci0 + j) * 256 + co]);
    store8(&WtP[id2 * 8], o);
  } else if (id < 330240) {
    int id3 = id - 327680;
    int li = id3 & 63; int rest = id3 >> 6;  // 0..39
    int kc = rest / 5, nt = rest % 5;
    int nc  = nt * 16 + (li & 15);
    int ci0 = kc * 32 + (li >> 4) * 8;
#pragma unroll
    for (int j = 0; j < 8; j++) o[j] = f2h(Wm[(ci0 + j) * 80 + nc]);
    store8(&WmP[id3 * 8], o);
  }
}

// ---------------------------------------------------------------------------
// conv3x3 SAME, 256->256, relu(x+b). Block = (roi, co-split cs, M-half).
// NF = co-fragments per wave (4 -> whole co-256 per block; 2 -> half).
// NF=2: acc 7x2 (56 AGPR) -> 3 blocks/CU (launch_bounds(256,3)); the two
// cs-blocks of a roi are dispatch-adjacent (bx = roi*2+cs) for input L2 reuse.
// sA: unpadded 256 B rows, T2 chunk-XOR swizzle (chunk ^ (pix&15)) on both
// staging writes and fragment reads -> breaks the A-read bank conflict.
// Tap rotation (L2 weight spread) + B double-prefetch kept.
// (s_setprio removed this round to de-risk the container failures.)
// ---------------------------------------------------------------------------
template <bool INF32, int NF>
__global__ __launch_bounds__(256, NF == 2 ? 3 : 2)
void conv_layer(const void* __restrict__ in_, const u16* __restrict__ WbP,
                const float* __restrict__ bc, u16* __restrict__ out, int layer) {
  __shared__ u16 sA[126 * 128 + 128];        // 126 rows x 256B, swizzled + zero page
  const int ZP = 126 * 128;
  const int tid = threadIdx.x;
  const int w = tid >> 6, lane = tid & 63, q = lane >> 4, r = lane & 15;
  const int CS = 4 / NF;                     // co-splits (1 or 2)
  const int roi = blockIdx.x / CS, cs = blockIdx.x % CS;
  const int mhalf = blockIdx.y;
  const int mbase = mhalf * 112;
  const int base_px = mhalf ? 98 : 0;        // first staged pixel (row_lo * 14)
  const int n_px   = mhalf ? 98 : 126;       // staged pixels (rows 7..13 / 0..8)
  const int rot = (roi + mhalf) % 9;
  if (tid < 64) ((u32*)(sA + ZP))[tid] = 0u;

  int py[7], px[7];
#pragma unroll
  for (int mt = 0; mt < 7; mt++) {
    int p = mbase + mt * 16 + r;
    py[mt] = (p < 196) ? (p / 14) : 1000;    // 1000 => always invalid after +dy
    px[mt] = p % 14;
  }
  f32x4 acc[7][NF];
#pragma unroll
  for (int mt = 0; mt < 7; mt++)
#pragma unroll
    for (int nf = 0; nf < NF; nf++) acc[mt][nf] = (f32x4){0.f, 0.f, 0.f, 0.f};

  const float* xrow = (const float*)in_ + ((size_t)roi * 196 + base_px) * 256;
  const u16*   yrow = (const u16*)in_   + ((size_t)roi * 196 + base_px) * 256;

  // wave's first co-tile; per-(tap,kc,nf) elem offset: tap*65536 + kc*8192 + nf*512
  const int ct0 = cs * (4 * NF) + w * NF;
  const u16* wb = WbP + (size_t)layer * 589824 + ct0 * 512 + lane * 8;

  f16x8 b0[NF], b1[NF];
#pragma unroll
  for (int nf = 0; nf < NF; nf++)
    b0[nf] = *(const f16x8*)&wb[rot * 65536 + nf * 512];   // (tap=rot, kc=0)

  for (int kh = 0; kh < 2; kh++) {
    if (kh) __syncthreads();
    if (INF32) {
      for (int c = tid; c < n_px * 32; c += 256) {
        int pix = c >> 5, cc = c & 31;       // cc = 8-byte granule (0..31)
        const float4 v = *(const float4*)&xrow[pix * 256 + kh * 128 + cc * 4];
        ushort4 h; h.x = f2h(v.x); h.y = f2h(v.y); h.z = f2h(v.z); h.w = f2h(v.w);
        int e = pix * 128 + (((cc >> 1) ^ (pix & 15)) << 3) + ((cc & 1) << 2);
        *(ushort4*)&sA[e] = h;
      }
    } else {
      for (int c = tid; c < n_px * 16; c += 256) {
        int pix = c >> 4, ch = c & 15;       // 16B chunk index
        int e = pix * 128 + ((ch ^ (pix & 15)) << 3);
        *(uint4*)&sA[e] = *(const uint4*)&yrow[pix * 256 + kh * 128 + ch * 8];
      }
    }
    __syncthreads();

    for (int t = 0; t < 9; t++) {
      int tap = t + rot; if (tap >= 9) tap -= 9;
      const int dy = tap / 3 - 1, dx = tap % 3 - 1;
      int base_e[7], sw8[7];
#pragma unroll
      for (int mt = 0; mt < 7; mt++) {
        int ny = py[mt] + dy, nx = px[mt] + dx;
        bool v = ((u32)ny < 14u) && ((u32)nx < 14u);
        int pixg = (ny * 14 + nx) - base_px;
        base_e[mt] = v ? pixg * 128 : ZP;
        sw8[mt]    = v ? ((pixg & 15) << 3) : 0;
      }
#pragma unroll
      for (int kk = 0; kk < 4; kk++) {
        // ---- next pipeline step's (tap, kh, kk) for the B prefetch ----
        int nt = t, nh = kh, nk = kk + 1;
        if (kk == 3) {
          nk = 0; nt = t + 1;
          if (nt == 9) {
            if (kh == 0) { nt = 0; nh = 1; }          // cross into half 1
            else         { nt = 8; nh = 1; nk = 3; }  // very last: benign reload
          }
        }
        int ntap = nt + rot; if (ntap >= 9) ntap -= 9;
        const u16* wn = wb + (ntap * 8 + nh * 4 + nk) * 8192;
        const int ck8 = kk * 32 + q * 8;     // chunk byte-swizzled frag offset
        if ((kk & 1) == 0) {
#pragma unroll
          for (int nf = 0; nf < NF; nf++) b1[nf] = *(const f16x8*)&wn[nf * 512];
#pragma unroll
          for (int mt = 0; mt < 7; mt++) {
            f16x8 a = *(const f16x8*)&sA[base_e[mt] + (ck8 ^ sw8[mt])];
#pragma unroll
            for (int nf = 0; nf < NF; nf++)
              acc[mt][nf] = __builtin_amdgcn_mfma_f32_16x16x32_f16(a, b0[nf], acc[mt][nf], 0, 0, 0);
          }
        } else {
#pragma unroll
          for (int nf = 0; nf < NF; nf++) b0[nf] = *(const f16x8*)&wn[nf * 512];
#pragma unroll
          for (int mt = 0; mt < 7; mt++) {
            f16x8 a = *(const f16x8*)&sA[base_e[mt] + (ck8 ^ sw8[mt])];
#pragma unroll
            for (int nf = 0; nf < NF; nf++)
              acc[mt][nf] = __builtin_amdgcn_mfma_f32_16x16x32_f16(a, b1[nf], acc[mt][nf], 0, 0, 0);
          }
        }
      }
    }
  }

  float bias[NF];
#pragma unroll
  for (int nf = 0; nf < NF; nf++) bias[nf] = bc[layer * 256 + (ct0 + nf) * 16 + r];
#pragma unroll
  for (int mt = 0; mt < 7; mt++) {
#pragma unroll
    for (int jj = 0; jj < 4; jj++) {
      int p = mbase + mt * 16 + q * 4 + jj;  // C/D: row = q*4+reg, col = r
      if (p < 196) {
#pragma unroll
        for (int nf = 0; nf < NF; nf++) {
          float v = acc[mt][nf][jj] + bias[nf];
          v = fmaxf(v, 0.f);
          out[((size_t)roi * 196 + p) * 256 + (ct0 + nf) * 16 + r] = f2h(v);
        }
      }
    }
  }
}

// ---------------------------------------------------------------------------
// Fused transpose-conv (2x2 s2 VALID, per-quadrant 1x1 GEMM) + relu + 1x1 mask.
// Block = (roi, quadrant ab, M-half). Phase 1: T = relu(y4 x WtP[ab] + bt)
// -> LDS tile [112][264] fp16. Phase 2: out = T x Wm + bm (N=80 = 5 tiles).
// (R1 version.)
// ---------------------------------------------------------------------------
__global__ __launch_bounds__(256, 2)
void tail_fused(const u16* __restrict__ y4, const u16* __restrict__ WtP,
                const u16* __restrict__ WmP, const float* __restrict__ bt,
                const float* __restrict__ bm, float* __restrict__ out) {
  __shared__ u16 sA[112 * 264 + 128];
  const int ZP = 112 * 264;
  const int tid = threadIdx.x;
  const int w = tid >> 6, lane = tid & 63, q = lane >> 4, r = lane & 15;
  const int roi = blockIdx.x, ab = blockIdx.y, mbase = blockIdx.z * 112;
  const int n_px = mbase ? 84 : 112;
  if (tid < 64) ((u32*)(sA + ZP))[tid] = 0u;

  int offs[7];
#pragma unroll
  for (int mt = 0; mt < 7; mt++) {
    int p = mbase + mt * 16 + r;
    offs[mt] = (p < 196) ? (mt * 16 + r) * 136 : ZP;
  }
  f32x4 acc[7][4];
#pragma unroll
  for (int mt = 0; mt < 7; mt++)
#pragma unroll
    for (int nf = 0; nf < 4; nf++) acc[mt][nf] = (f32x4){0.f, 0.f, 0.f, 0.f};

  const u16* wt = WtP + ab * 65536 + (w * 4) * 512 + lane * 8;  // off: kc*8192+nf*512
  f16x8 b0[4], b1[4];
#pragma unroll
  for (int nf = 0; nf < 4; nf++) b0[nf] = *(const f16x8*)&wt[nf * 512];  // kc=0

  for (int kh = 0; kh < 2; kh++) {
    if (kh) __syncthreads();
    for (int c = tid; c < n_px * 16; c += 256) {
      int pix = c >> 4, c8 = (c & 15) * 8;
      *(uint4*)&sA[pix * 136 + c8] =
          *(const uint4*)&y4[((size_t)roi * 196 + mbase + pix) * 256 + kh * 128 + c8];
    }
    __syncthreads();
#pragma unroll
    for (int kk = 0; kk < 4; kk++) {
      int nc_ = kh * 4 + kk + 1; if (nc_ > 7) nc_ = 7;   // next kc (clamped)
      const u16* wn = wt + nc_ * 8192;
      if ((kk & 1) == 0) {
#pragma unroll
        for (int nf = 0; nf < 4; nf++) b1[nf] = *(const f16x8*)&wn[nf * 512];
#pragma unroll
        for (int mt = 0; mt < 7; mt++) {
          f16x8 a = *(const f16x8*)&sA[offs[mt] + kk * 32 + q * 8];
#pragma unroll
          for (int nf = 0; nf < 4; nf++)
            acc[mt][nf] = __builtin_amdgcn_mfma_f32_16x16x32_f16(a, b0[nf], acc[mt][nf], 0, 0, 0);
        }
      } else {
#pragma unroll
        for (int nf = 0; nf < 4; nf++) b0[nf] = *(const f16x8*)&wn[nf * 512];
#pragma unroll
        for (int mt = 0; mt < 7; mt++) {
          f16x8 a = *(const f16x8*)&sA[offs[mt] + kk * 32 + q * 8];
#pragma unroll
          for (int nf = 0; nf < 4; nf++)
            acc[mt][nf] = __builtin_amdgcn_mfma_f32_16x16x32_f16(a, b1[nf], acc[mt][nf], 0, 0, 0);
        }
      }
    }
  }

  __syncthreads();                           // all K-loop LDS reads done
  float btv[4];
#pragma unroll
  for (int nf = 0; nf < 4; nf++) btv[nf] = bt[(w * 4 + nf) * 16 + r];
#pragma unroll
  for (int mt = 0; mt < 7; mt++) {
#pragma unroll
    for (int jj = 0; jj < 4; jj++) {
      int row = mt * 16 + q * 4 + jj;        // 0..111
#pragma unroll
      for (int nf = 0; nf < 4; nf++) {
        float v = fmaxf(acc[mt][nf][jj] + btv[nf], 0.f);
        sA[row * 264 + (w * 4 + nf) * 16 + r] = f2h(v);
      }
    }
  }
  __syncthreads();

  float bmv[5];
#pragma unroll
  for (int nt = 0; nt < 5; nt++) bmv[nt] = bm[nt * 16 + r];
  const int a_ = ab >> 1, b_ = ab & 1;
  for (int tt = w; tt < 7; tt += 4) {
    f32x4 a2[5];
#pragma unroll
    for (int nt = 0; nt < 5; nt++) a2[nt] = (f32x4){0.f, 0.f, 0.f, 0.f};
#pragma unroll
    for (int kc = 0; kc < 8; kc++) {
      f16x8 af = *(const f16x8*)&sA[(tt * 16 + r) * 264 + kc * 32 + q * 8];
#pragma unroll
      for (int nt = 0; nt < 5; nt++) {
        f16x8 bw = *(const f16x8*)&WmP[((kc * 5 + nt) * 64 + lane) * 8];
        a2[nt] = __builtin_amdgcn_mfma_f32_16x16x32_f16(af, bw, a2[nt], 0, 0, 0);
      }
    }
#pragma unroll
    for (int jj = 0; jj < 4; jj++) {
      int row = tt * 16 + q * 4 + jj;
      int p = mbase + row;
      if (p < 196) {
        int y = p / 14, x = p % 14;
        size_t base = (size_t)roi * 62720 + (2 * y + a_) * 2240 + (2 * x + b_) * 80;
#pragma unroll
        for (int nt = 0; nt < 5; nt++) out[base + nt * 16 + r] = a2[nt][jj] + bmv[nt];
      }
    }
  }
}

// ---------------------------------------------------------------------------
extern "C" void kernel_launch(void* const* d_in, const int* in_sizes, int n_in,
                              void* d_out, int out_size, void* d_ws, size_t ws_size,
                              hipStream_t stream) {
  const float* x  = (const float*)d_in[0];
  const float* Wc = (const float*)d_in[1];
  const float* bc = (const float*)d_in[2];
  const float* Wt = (const float*)d_in[3];
  const float* bt = (const float*)d_in[4];
  const float* Wm = (const float*)d_in[5];
  const float* bm = (const float*)d_in[6];
  float* out = (float*)d_out;

  char* ws = (char*)d_ws;
  u16* WbP = (u16*)(ws);                         // 4,718,592 B
  u16* WtP = (u16*)(ws + 4718592);               //   524,288 B
  u16* WmP = (u16*)(ws + 5242880);               //    40,960 B
  u16* yA  = (u16*)(ws + 6291456);               // 102,760,448 B
  u16* yB  = (u16*)(ws + 6291456 + 102760448);   // 102,760,448 B  (total ~212 MB)

  prep_weights<<<1290, 256, 0, stream>>>(Wc, Wt, Wm, WbP, WtP, WmP);

  // layer 0: f32 input, whole-co blocks (NF=4). layers 1-3: co-split (NF=2),
  // bx = roi*2 + cs so the two co-blocks of a roi are dispatch-adjacent (L2).
  conv_layer<true , 4><<<dim3(1024, 2), 256, 0, stream>>>(x,  WbP, bc, yA, 0);
  conv_layer<false, 2><<<dim3(2048, 2), 256, 0, stream>>>(yA, WbP, bc, yB, 1);
  conv_layer<false, 2><<<dim3(2048, 2), 256, 0, stream>>>(yB, WbP, bc, yA, 2);
  conv_layer<false, 2><<<dim3(2048, 2), 256, 0, stream>>>(yA, WbP, bc, yB, 3);

  tail_fused<<<dim3(1024, 4, 2), 256, 0, stream>>>(yB, WtP, WmP, bt, bm, out);
}

// Round 6
// 1488.180 us; speedup vs baseline: 1.0522x; 1.0075x over previous
//
#include <hip/hip_runtime.h>

// ROIMaskHead: x[1024,14,14,256] f32 -> 4x (conv3x3 256->256 + relu) ->
// conv_transpose 2x2 s2 + relu -> 1x1 conv ->80, out [1024,28,28,80] f32.
// All matmuls via mfma_f32_16x16x32_f16; activations/weights fp16, acc f32.

typedef _Float16 f16x8 __attribute__((ext_vector_type(8)));
typedef float    f32x4 __attribute__((ext_vector_type(4)));
typedef unsigned short u16;
typedef unsigned int   u32;

__device__ __forceinline__ u16 f2h(float f) {
  union { _Float16 h; u16 u; } c; c.h = (_Float16)f; return c.u;
}

__device__ __forceinline__ void store8(u16* dst, const u16* o) {
  uint4 v;
  v.x = (u32)o[0] | ((u32)o[1] << 16);
  v.y = (u32)o[2] | ((u32)o[3] << 16);
  v.z = (u32)o[4] | ((u32)o[5] << 16);
  v.w = (u32)o[6] | ((u32)o[7] << 16);
  *(uint4*)dst = v;
}

// ---------------------------------------------------------------------------
// Weight repack to MFMA B-fragment order (one coalesced dwordx4 per lane):
// WbP[l][tap][kc][cotile][lane=q*16+rr][j] = Wc[l][tap][ci=kc*32+q*8+j][co=ct*16+rr]
// WtP[ab][kc][ct][lane][j]                = Wt[3-ab][ci][co]   (spatial flip)
// WmP[kc][nt][lane][j]                    = Wm[ci][nc=nt*16+rr]
// ---------------------------------------------------------------------------
__global__ void prep_weights(const float* __restrict__ Wc, const float* __restrict__ Wt,
                             const float* __restrict__ Wm,
                             u16* __restrict__ WbP, u16* __restrict__ WtP,
                             u16* __restrict__ WmP) {
  int id = blockIdx.x * 256 + threadIdx.x;
  u16 o[8];
  if (id < 294912) {
    int li = id & 63; int rest = id >> 6;
    int ct = rest & 15; rest >>= 4;
    int kc = rest & 7;  rest >>= 3;          // rest = l*9+tap (0..35)
    int co  = ct * 16 + (li & 15);
    int ci0 = kc * 32 + (li >> 4) * 8;
#pragma unroll
    for (int j = 0; j < 8; j++) o[j] = f2h(Wc[(rest * 256 + ci0 + j) * 256 + co]);
    store8(&WbP[id * 8], o);
  } else if (id < 327680) {
    int id2 = id - 294912;
    int li = id2 & 63; int rest = id2 >> 6;
    int ct = rest & 15; rest >>= 4;
    int kc = rest & 7;  rest >>= 3;          // rest = ab (0..3)
    int srcq = 3 - rest;                     // kernel flip for conv_transpose
    int co  = ct * 16 + (li & 15);
    int ci0 = kc * 32 + (li >> 4) * 8;
#pragma unroll
    for (int j = 0; j < 8; j++) o[j] = f2h(Wt[(srcq * 256 + ci0 + j) * 256 + co]);
    store8(&WtP[id2 * 8], o);
  } else if (id < 330240) {
    int id3 = id - 327680;
    int li = id3 & 63; int rest = id3 >> 6;  // 0..39
    int kc = rest / 5, nt = rest % 5;
    int nc  = nt * 16 + (li & 15);
    int ci0 = kc * 32 + (li >> 4) * 8;
#pragma unroll
    for (int j = 0; j < 8; j++) o[j] = f2h(Wm[(ci0 + j) * 80 + nc]);
    store8(&WmP[id3 * 8], o);
  }
}

// ---------------------------------------------------------------------------
// conv3x3 SAME, 256->256, relu(x+b). One block = (roi, M-half of 112 px).
// 4 waves x (7 Mtiles x 4 Nfrags); K staged in 128-ci halves in LDS (pad 136).
// R6: in-register A-fragment prefetch for mt 0..2 -- step s+1's first 3 frags
// are read during step s's MFMA burst (static kk&1 parity: pA*/pB*). Each step
// opens with 12 MFMAs on resident data, covering the in-step reads for mt 3..6.
// Prefetch guarded at the kh restage boundary. Weight depth-1 prefetch (b0/b1)
// + tap rotation + windowed row staging kept from R1. No LDS swizzle (the R5
// experiment showed conflicts are not the bottleneck; the XOR cost VALU).
// ---------------------------------------------------------------------------
template <bool INF32>
__global__ __launch_bounds__(256, 2)
void conv_layer(const void* __restrict__ in_, const u16* __restrict__ WbP,
                const float* __restrict__ bc, u16* __restrict__ out, int layer) {
  __shared__ u16 sA[126 * 136 + 128];
  const int ZP = 126 * 136;
  const int tid = threadIdx.x;
  const int w = tid >> 6, lane = tid & 63, q = lane >> 4, r = lane & 15;
  const int roi = blockIdx.x, mhalf = blockIdx.y;
  const int mbase = mhalf * 112;
  const int base_px = mhalf ? 98 : 0;      // first staged pixel (row_lo * 14)
  const int n_px   = mhalf ? 98 : 126;     // staged pixel count (rows 7..13 / 0..8)
  const int rot = (roi + mhalf) % 9;
  const int aoff = q * 8;
  if (tid < 64) ((u32*)(sA + ZP))[tid] = 0u;

  int py[7], px[7];
#pragma unroll
  for (int mt = 0; mt < 7; mt++) {
    int p = mbase + mt * 16 + r;
    py[mt] = (p < 196) ? (p / 14) : 1000;   // 1000 => always invalid after +dy
    px[mt] = p % 14;
  }
  f32x4 acc[7][4];
#pragma unroll
  for (int mt = 0; mt < 7; mt++)
#pragma unroll
    for (int nf = 0; nf < 4; nf++) acc[mt][nf] = (f32x4){0.f, 0.f, 0.f, 0.f};

  const float* xrow = (const float*)in_ + ((size_t)roi * 196 + base_px) * 256;
  const u16*   yrow = (const u16*)in_   + ((size_t)roi * 196 + base_px) * 256;

  // per-(wave,lane) weight base; elem offset for (tap,kc,nf): tap*65536+kc*8192+nf*512
  const u16* wb = WbP + (size_t)layer * 589824 + (w * 4) * 512 + lane * 8;

  f16x8 b0[4], b1[4];
#pragma unroll
  for (int nf = 0; nf < 4; nf++)
    b0[nf] = *(const f16x8*)&wb[rot * 65536 + nf * 512];   // (tap=rot, kc=0)

  f16x8 pA0, pA1, pA2, pB0, pB1, pB2;      // A-prefetch ping-pong (mt 0..2)

  for (int kh = 0; kh < 2; kh++) {
    if (kh) __syncthreads();
    if (INF32) {
      for (int c = tid; c < n_px * 32; c += 256) {
        int pix = c >> 5, c4 = (c & 31) * 4;
        const float4 v = *(const float4*)&xrow[pix * 256 + kh * 128 + c4];
        ushort4 h; h.x = f2h(v.x); h.y = f2h(v.y); h.z = f2h(v.z); h.w = f2h(v.w);
        *(ushort4*)&sA[pix * 136 + c4] = h;
      }
    } else {
      for (int c = tid; c < n_px * 16; c += 256) {
        int pix = c >> 4, c8 = (c & 15) * 8;
        *(uint4*)&sA[pix * 136 + c8] =
            *(const uint4*)&yrow[pix * 256 + kh * 128 + c8];
      }
    }
    __syncthreads();

    // prologue: fill pA* for (tap=rot, kk=0)
    {
      const int dy = rot / 3 - 1, dx = rot % 3 - 1;
#pragma unroll
      for (int m = 0; m < 3; m++) {
        int ny = py[m] + dy, nx = px[m] + dx;
        bool v = ((u32)ny < 14u) && ((u32)nx < 14u);
        int o = v ? ((ny * 14 + nx) - base_px) * 136 : ZP;
        f16x8 tf = *(const f16x8*)&sA[o + aoff];
        if (m == 0) pA0 = tf; else if (m == 1) pA1 = tf; else pA2 = tf;
      }
    }

    for (int t = 0; t < 9; t++) {
      int tap = t + rot; if (tap >= 9) tap -= 9;
      const int dy = tap / 3 - 1, dx = tap % 3 - 1;
      int offs[7];
#pragma unroll
      for (int mt = 0; mt < 7; mt++) {
        int ny = py[mt] + dy, nx = px[mt] + dx;
        bool v = ((u32)ny < 14u) && ((u32)nx < 14u);
        offs[mt] = v ? ((ny * 14 + nx) - base_px) * 136 : ZP;
      }
      // next tap's offsets for mt 0..2 (consumed by the kk=3 prefetch)
      int offs3n[3];
      {
        int tap2 = tap + 1; if (tap2 >= 9) tap2 -= 9;
        const int dy2 = tap2 / 3 - 1, dx2 = tap2 % 3 - 1;
#pragma unroll
        for (int m = 0; m < 3; m++) {
          int ny = py[m] + dy2, nx = px[m] + dx2;
          bool v = ((u32)ny < 14u) && ((u32)nx < 14u);
          offs3n[m] = v ? ((ny * 14 + nx) - base_px) * 136 : ZP;
        }
      }
      const bool pf_last = (t < 8);          // no cross-restage prefetch

#pragma unroll
      for (int kk = 0; kk < 4; kk++) {
        // ---- next pipeline step's (tap, kh, kk) for the B prefetch ----
        int nt = t, nh = kh, nk = kk + 1;
        if (kk == 3) {
          nk = 0; nt = t + 1;
          if (nt == 9) {
            if (kh == 0) { nt = 0; nh = 1; }          // cross into half 1
            else         { nt = 8; nh = 1; nk = 3; }  // very last: benign reload
          }
        }
        int ntap = nt + rot; if (ntap >= 9) ntap -= 9;
        const u16* wn = wb + (ntap * 8 + nh * 4 + nk) * 8192;

        if ((kk & 1) == 0) {                 // even step: A cur = pA*, fill pB*
#pragma unroll
          for (int nf = 0; nf < 4; nf++) b1[nf] = *(const f16x8*)&wn[nf * 512];
          f16x8 a3 = *(const f16x8*)&sA[offs[3] + kk * 32 + aoff];
          f16x8 a4 = *(const f16x8*)&sA[offs[4] + kk * 32 + aoff];
          f16x8 a5 = *(const f16x8*)&sA[offs[5] + kk * 32 + aoff];
          f16x8 a6 = *(const f16x8*)&sA[offs[6] + kk * 32 + aoff];
          // prefetch next step's mt 0..2 (kk<3 is compile-time here: kk=0,2)
          pB0 = *(const f16x8*)&sA[offs[0] + (kk + 1) * 32 + aoff];
          pB1 = *(const f16x8*)&sA[offs[1] + (kk + 1) * 32 + aoff];
          pB2 = *(const f16x8*)&sA[offs[2] + (kk + 1) * 32 + aoff];
#pragma unroll
          for (int nf = 0; nf < 4; nf++)
            acc[0][nf] = __builtin_amdgcn_mfma_f32_16x16x32_f16(pA0, b0[nf], acc[0][nf], 0, 0, 0);
#pragma unroll
          for (int nf = 0; nf < 4; nf++)
            acc[1][nf] = __builtin_amdgcn_mfma_f32_16x16x32_f16(pA1, b0[nf], acc[1][nf], 0, 0, 0);
#pragma unroll
          for (int nf = 0; nf < 4; nf++)
            acc[2][nf] = __builtin_amdgcn_mfma_f32_16x16x32_f16(pA2, b0[nf], acc[2][nf], 0, 0, 0);
#pragma unroll
          for (int nf = 0; nf < 4; nf++)
            acc[3][nf] = __builtin_amdgcn_mfma_f32_16x16x32_f16(a3, b0[nf], acc[3][nf], 0, 0, 0);
#pragma unroll
          for (int nf = 0; nf < 4; nf++)
            acc[4][nf] = __builtin_amdgcn_mfma_f32_16x16x32_f16(a4, b0[nf], acc[4][nf], 0, 0, 0);
#pragma unroll
          for (int nf = 0; nf < 4; nf++)
            acc[5][nf] = __builtin_amdgcn_mfma_f32_16x16x32_f16(a5, b0[nf], acc[5][nf], 0, 0, 0);
#pragma unroll
          for (int nf = 0; nf < 4; nf++)
            acc[6][nf] = __builtin_amdgcn_mfma_f32_16x16x32_f16(a6, b0[nf], acc[6][nf], 0, 0, 0);
        } else {                             // odd step: A cur = pB*, fill pA*
#pragma unroll
          for (int nf = 0; nf < 4; nf++) b0[nf] = *(const f16x8*)&wn[nf * 512];
          f16x8 a3 = *(const f16x8*)&sA[offs[3] + kk * 32 + aoff];
          f16x8 a4 = *(const f16x8*)&sA[offs[4] + kk * 32 + aoff];
          f16x8 a5 = *(const f16x8*)&sA[offs[5] + kk * 32 + aoff];
          f16x8 a6 = *(const f16x8*)&sA[offs[6] + kk * 32 + aoff];
          if (kk < 3) {                      // kk=1: same-tap next slice
            pA0 = *(const f16x8*)&sA[offs[0] + (kk + 1) * 32 + aoff];
            pA1 = *(const f16x8*)&sA[offs[1] + (kk + 1) * 32 + aoff];
            pA2 = *(const f16x8*)&sA[offs[2] + (kk + 1) * 32 + aoff];
          } else if (pf_last) {              // kk=3: next tap, kk=0
            pA0 = *(const f16x8*)&sA[offs3n[0] + aoff];
            pA1 = *(const f16x8*)&sA[offs3n[1] + aoff];
            pA2 = *(const f16x8*)&sA[offs3n[2] + aoff];
          }
#pragma unroll
          for (int nf = 0; nf < 4; nf++)
            acc[0][nf] = __builtin_amdgcn_mfma_f32_16x16x32_f16(pB0, b1[nf], acc[0][nf], 0, 0, 0);
#pragma unroll
          for (int nf = 0; nf < 4; nf++)
            acc[1][nf] = __builtin_amdgcn_mfma_f32_16x16x32_f16(pB1, b1[nf], acc[1][nf], 0, 0, 0);
#pragma unroll
          for (int nf = 0; nf < 4; nf++)
            acc[2][nf] = __builtin_amdgcn_mfma_f32_16x16x32_f16(pB2, b1[nf], acc[2][nf], 0, 0, 0);
#pragma unroll
          for (int nf = 0; nf < 4; nf++)
            acc[3][nf] = __builtin_amdgcn_mfma_f32_16x16x32_f16(a3, b1[nf], acc[3][nf], 0, 0, 0);
#pragma unroll
          for (int nf = 0; nf < 4; nf++)
            acc[4][nf] = __builtin_amdgcn_mfma_f32_16x16x32_f16(a4, b1[nf], acc[4][nf], 0, 0, 0);
#pragma unroll
          for (int nf = 0; nf < 4; nf++)
            acc[5][nf] = __builtin_amdgcn_mfma_f32_16x16x32_f16(a5, b1[nf], acc[5][nf], 0, 0, 0);
#pragma unroll
          for (int nf = 0; nf < 4; nf++)
            acc[6][nf] = __builtin_amdgcn_mfma_f32_16x16x32_f16(a6, b1[nf], acc[6][nf], 0, 0, 0);
        }
      }
    }
  }

  float bias[4];
#pragma unroll
  for (int nf = 0; nf < 4; nf++) bias[nf] = bc[layer * 256 + (w * 4 + nf) * 16 + r];
#pragma unroll
  for (int mt = 0; mt < 7; mt++) {
#pragma unroll
    for (int jj = 0; jj < 4; jj++) {
      int p = mbase + mt * 16 + q * 4 + jj;   // C/D: row = q*4+reg, col = r
      if (p < 196) {
#pragma unroll
        for (int nf = 0; nf < 4; nf++) {
          float v = acc[mt][nf][jj] + bias[nf];
          v = fmaxf(v, 0.f);
          out[((size_t)roi * 196 + p) * 256 + (w * 4 + nf) * 16 + r] = f2h(v);
        }
      }
    }
  }
}

// ---------------------------------------------------------------------------
// Fused transpose-conv (2x2 s2 VALID, per-quadrant 1x1 GEMM) + relu + 1x1 mask.
// Block = (roi, quadrant ab, M-half). Phase 1: T = relu(y4 x WtP[ab] + bt)
// -> LDS tile [112][264] fp16. Phase 2: out = T x Wm + bm (N=80 = 5 tiles).
// (R1 version.)
// ---------------------------------------------------------------------------
__global__ __launch_bounds__(256, 2)
void tail_fused(const u16* __restrict__ y4, const u16* __restrict__ WtP,
                const u16* __restrict__ WmP, const float* __restrict__ bt,
                const float* __restrict__ bm, float* __restrict__ out) {
  __shared__ u16 sA[112 * 264 + 128];
  const int ZP = 112 * 264;
  const int tid = threadIdx.x;
  const int w = tid >> 6, lane = tid & 63, q = lane >> 4, r = lane & 15;
  const int roi = blockIdx.x, ab = blockIdx.y, mbase = blockIdx.z * 112;
  const int n_px = mbase ? 84 : 112;
  if (tid < 64) ((u32*)(sA + ZP))[tid] = 0u;

  int offs[7];
#pragma unroll
  for (int mt = 0; mt < 7; mt++) {
    int p = mbase + mt * 16 + r;
    offs[mt] = (p < 196) ? (mt * 16 + r) * 136 : ZP;
  }
  f32x4 acc[7][4];
#pragma unroll
  for (int mt = 0; mt < 7; mt++)
#pragma unroll
    for (int nf = 0; nf < 4; nf++) acc[mt][nf] = (f32x4){0.f, 0.f, 0.f, 0.f};

  const u16* wt = WtP + ab * 65536 + (w * 4) * 512 + lane * 8;  // off: kc*8192+nf*512
  f16x8 b0[4], b1[4];
#pragma unroll
  for (int nf = 0; nf < 4; nf++) b0[nf] = *(const f16x8*)&wt[nf * 512];  // kc=0

  for (int kh = 0; kh < 2; kh++) {
    if (kh) __syncthreads();
    for (int c = tid; c < n_px * 16; c += 256) {
      int pix = c >> 4, c8 = (c & 15) * 8;
      *(uint4*)&sA[pix * 136 + c8] =
          *(const uint4*)&y4[((size_t)roi * 196 + mbase + pix) * 256 + kh * 128 + c8];
    }
    __syncthreads();
#pragma unroll
    for (int kk = 0; kk < 4; kk++) {
      int nc_ = kh * 4 + kk + 1; if (nc_ > 7) nc_ = 7;   // next kc (clamped)
      const u16* wn = wt + nc_ * 8192;
      if ((kk & 1) == 0) {
#pragma unroll
        for (int nf = 0; nf < 4; nf++) b1[nf] = *(const f16x8*)&wn[nf * 512];
#pragma unroll
        for (int mt = 0; mt < 7; mt++) {
          f16x8 a = *(const f16x8*)&sA[offs[mt] + kk * 32 + q * 8];
#pragma unroll
          for (int nf = 0; nf < 4; nf++)
            acc[mt][nf] = __builtin_amdgcn_mfma_f32_16x16x32_f16(a, b0[nf], acc[mt][nf], 0, 0, 0);
        }
      } else {
#pragma unroll
        for (int nf = 0; nf < 4; nf++) b0[nf] = *(const f16x8*)&wn[nf * 512];
#pragma unroll
        for (int mt = 0; mt < 7; mt++) {
          f16x8 a = *(const f16x8*)&sA[offs[mt] + kk * 32 + q * 8];
#pragma unroll
          for (int nf = 0; nf < 4; nf++)
            acc[mt][nf] = __builtin_amdgcn_mfma_f32_16x16x32_f16(a, b1[nf], acc[mt][nf], 0, 0, 0);
        }
      }
    }
  }

  __syncthreads();                           // all K-loop LDS reads done
  float btv[4];
#pragma unroll
  for (int nf = 0; nf < 4; nf++) btv[nf] = bt[(w * 4 + nf) * 16 + r];
#pragma unroll
  for (int mt = 0; mt < 7; mt++) {
#pragma unroll
    for (int jj = 0; jj < 4; jj++) {
      int row = mt * 16 + q * 4 + jj;        // 0..111
#pragma unroll
      for (int nf = 0; nf < 4; nf++) {
        float v = fmaxf(acc[mt][nf][jj] + btv[nf], 0.f);
        sA[row * 264 + (w * 4 + nf) * 16 + r] = f2h(v);
      }
    }
  }
  __syncthreads();

  float bmv[5];
#pragma unroll
  for (int nt = 0; nt < 5; nt++) bmv[nt] = bm[nt * 16 + r];
  const int a_ = ab >> 1, b_ = ab & 1;
  for (int tt = w; tt < 7; tt += 4) {
    f32x4 a2[5];
#pragma unroll
    for (int nt = 0; nt < 5; nt++) a2[nt] = (f32x4){0.f, 0.f, 0.f, 0.f};
#pragma unroll
    for (int kc = 0; kc < 8; kc++) {
      f16x8 af = *(const f16x8*)&sA[(tt * 16 + r) * 264 + kc * 32 + q * 8];
#pragma unroll
      for (int nt = 0; nt < 5; nt++) {
        f16x8 bw = *(const f16x8*)&WmP[((kc * 5 + nt) * 64 + lane) * 8];
        a2[nt] = __builtin_amdgcn_mfma_f32_16x16x32_f16(af, bw, a2[nt], 0, 0, 0);
      }
    }
#pragma unroll
    for (int jj = 0; jj < 4; jj++) {
      int row = tt * 16 + q * 4 + jj;
      int p = mbase + row;
      if (p < 196) {
        int y = p / 14, x = p % 14;
        size_t base = (size_t)roi * 62720 + (2 * y + a_) * 2240 + (2 * x + b_) * 80;
#pragma unroll
        for (int nt = 0; nt < 5; nt++) out[base + nt * 16 + r] = a2[nt][jj] + bmv[nt];
      }
    }
  }
}

// ---------------------------------------------------------------------------
extern "C" void kernel_launch(void* const* d_in, const int* in_sizes, int n_in,
                              void* d_out, int out_size, void* d_ws, size_t ws_size,
                              hipStream_t stream) {
  const float* x  = (const float*)d_in[0];
  const float* Wc = (const float*)d_in[1];
  const float* bc = (const float*)d_in[2];
  const float* Wt = (const float*)d_in[3];
  const float* bt = (const float*)d_in[4];
  const float* Wm = (const float*)d_in[5];
  const float* bm = (const float*)d_in[6];
  float* out = (float*)d_out;

  char* ws = (char*)d_ws;
  u16* WbP = (u16*)(ws);                         // 4,718,592 B
  u16* WtP = (u16*)(ws + 4718592);               //   524,288 B
  u16* WmP = (u16*)(ws + 5242880);               //    40,960 B
  u16* yA  = (u16*)(ws + 6291456);               // 102,760,448 B
  u16* yB  = (u16*)(ws + 6291456 + 102760448);   // 102,760,448 B  (total ~212 MB)

  prep_weights<<<1290, 256, 0, stream>>>(Wc, Wt, Wm, WbP, WtP, WmP);

  dim3 cg(1024, 2);
  conv_layer<true ><<<cg, 256, 0, stream>>>(x,  WbP, bc, yA, 0);
  conv_layer<false><<<cg, 256, 0, stream>>>(yA, WbP, bc, yB, 1);
  conv_layer<false><<<cg, 256, 0, stream>>>(yB, WbP, bc, yA, 2);
  conv_layer<false><<<cg, 256, 0, stream>>>(yA, WbP, bc, yB, 3);

  tail_fused<<<dim3(1024, 4, 2), 256, 0, stream>>>(yB, WtP, WmP, bt, bm, out);
}